// Round 9
// baseline (3386.729 us; speedup 1.0000x reference)
//
#include <hip/hip_runtime.h>
#include <math.h>

typedef unsigned long long u64;

namespace {
constexpr int kH    = 256;   // hidden
constexpr int kM    = 32;    // stack value dim
constexpr int kIn   = 131;   // input dim
constexpr int kOut  = 131;   // output dim
constexpr int kB    = 32;    // batch
constexpr int kTenc = 128;   // encoder steps
constexpr int kT    = 256;   // total sequential steps
constexpr int kCap  = 257;   // stack capacity
constexpr int kG    = 1024;  // 4*H gates
constexpr int kK    = 288;   // H + M combined recurrent input
constexpr int kSp   = 8;     // K-splits (cooperating blocks per batch)
constexpr int kKs   = 36;    // K per split (splits 0..6 pure-h; split 7 has the r cols)
constexpr int kWR   = 72;    // fp32 weights per thread (2 gates x 36 k) -> fits 128 VGPRs
constexpr int kVs   = 36;    // Vbuf row stride
}

__device__ __forceinline__ float frcp(float x){ return __builtin_amdgcn_rcpf(x); }
__device__ __forceinline__ float sigf(float x){ return frcp(1.0f + __expf(-x)); }
__device__ __forceinline__ float tanhf_fast(float x){
  return 1.0f - 2.0f*frcp(__expf(2.0f*x) + 1.0f);   // saturates via inf/0
}

template<int PAT>
__device__ __forceinline__ float swz(float x){
  return __int_as_float(__builtin_amdgcn_ds_swizzle(__float_as_int(x), PAT));
}

// dst[c*R + r] = src[r*stride + col0 + c]
__global__ void k_transpose(float* __restrict__ dst, const float* __restrict__ src,
                            int R, int C, int stride, int col0){
  int idx = blockIdx.x*256 + threadIdx.x;
  if (idx >= R*C) return;
  int rr = idx / C;
  int cc = idx - rr*C;
  dst[cc*R + rr] = src[rr*stride + col0 + cc];
}

// fp32 weight pack: dst[(s*kWR + i)*512 + tid], i = gs*kKs + kk
//   thread tid (j=tid&255, gp=tid>>8) gate col=(2gp+gs)*256+j, k = s*kKs+kk
//   k<256 -> Whh[col][k], else Wih[col][131 + (k-256)]
__global__ void k_packw(float* __restrict__ dst, const float* __restrict__ Wih,
                        const float* __restrict__ Whh){
  int idx = blockIdx.x*256 + threadIdx.x;
  if (idx >= kSp*kWR*512) return;
  int tid  = idx & 511;
  int rest = idx >> 9;             // s*kWR + i
  int s  = rest / kWR, i = rest - s*kWR;
  int gs = i / kKs,   kk = i - gs*kKs;
  int j  = tid & 255, gp = tid >> 8;
  int col = (2*gp + gs)*256 + j;
  int k   = s*kKs + kk;
  dst[idx] = (k < kH) ? Whh[col*kH + k] : Wih[col*(kIn+kM) + kIn + (k - kH)];
}

// gatesXp[t][b][j][g] = sum_k x_t[b][k]*Wih[g*256+j][k] + bih + bhh
__global__ void k_gatesx(const float* __restrict__ X, const float* __restrict__ Y,
                         const float* __restrict__ WixT_e, const float* __restrict__ WixT_d,
                         const float* __restrict__ bih_e, const float* __restrict__ bhh_e,
                         const float* __restrict__ bih_d, const float* __restrict__ bhh_d,
                         float* __restrict__ gatesXp){
  const int t   = blockIdx.x;
  const int col = blockIdx.y*256 + threadIdx.x;
  __shared__ float xl[kB*kIn];
  const float* xsrc;
  if (t < kTenc)       xsrc = X + (size_t)t*kB*kIn;
  else if (t == kTenc) xsrc = X + (size_t)kTenc*kB*kIn;
  else                 xsrc = Y + (size_t)(t-kTenc-1)*kB*kIn;
  for (int i = threadIdx.x; i < kB*kIn; i += 256) xl[i] = xsrc[i];
  __syncthreads();
  const float* WT   = (t < kTenc) ? WixT_e : WixT_d;
  const float  bias = (t < kTenc) ? (bih_e[col] + bhh_e[col]) : (bih_d[col] + bhh_d[col]);
  float acc[kB];
#pragma unroll
  for (int b = 0; b < kB; ++b) acc[b] = bias;
  for (int k = 0; k < kIn; ++k){
    float wk = WT[k*kG + col];
#pragma unroll
    for (int b = 0; b < kB; ++b) acc[b] += wk * xl[b*kIn + k];
  }
  const int j = col & 255, g = col >> 8;
#pragma unroll
  for (int b = 0; b < kB; ++b)
    gatesXp[(((size_t)t*kB + b)*256 + j)*4 + g] = acc[b];
}

__device__ __forceinline__ float wave_suffix_incl(float x, int lane){
#pragma unroll
  for (int off = 1; off < 64; off <<= 1){
    float t = __shfl_down(x, off);
    if (lane + off < 64) x += t;
  }
  return x;
}

__global__ void __launch_bounds__(512, 1)
k_seq(const float* __restrict__ gatesXp, const float* __restrict__ wblob,
      u64* __restrict__ pbuf2, unsigned int* flags,
      const float* __restrict__ Wd, const float* __restrict__ bd,
      const float* __restrict__ Wu, const float* __restrict__ bu,
      const float* __restrict__ Wv, const float* __restrict__ bv,
      const float* __restrict__ h0, const float* __restrict__ c0,
      float* __restrict__ Hdec){
  const int bid  = blockIdx.x;
  const int b    = bid >> 3;       // batch element
  const int sp   = bid & 7;        // K-split id 0..7 (7 = stack owner)
  const int tid  = threadIdx.x;
  const int lane = tid & 63;
  const int wave = tid >> 6;
  const int j    = tid & 255;
  const int gp   = tid >> 8;       // 0: gates i,f ; 1: gates g,o

  __shared__ __align__(16) float z[kK];   // [h(256) | r(32)]
  __shared__ float cst[kH];
  __shared__ float gbuf[2][256];          // g,o gates exchange (intra-block)
  __shared__ float sbuf[kCap];            // stack state: only sp==7 uses
  __shared__ float coeff[kCap];
  __shared__ float Vbuf[kCap*kVs];

  if (tid < kH){ z[tid] = h0[tid]; cst[tid] = c0[tid]; }
  if (tid >= kH && tid < kK) z[tid] = 0.f;
  for (int i = tid; i < kCap; i += 512) sbuf[i] = 0.f;
  if (tid < kVs) Vbuf[tid] = 0.f;         // row 0 (never written, coeff=0)
  __syncthreads();

  float wreg[kWR];
  {
    const float* wb = wblob + ((size_t)sp*kWR)*512 + tid;   // encoder slice
#pragma unroll
    for (int i = 0; i < kWR; ++i) wreg[i] = wb[(size_t)i*512];
#pragma unroll
    for (int i = 0; i < kWR; ++i) asm volatile("" : "+v"(wreg[i]));
  }

  // matvec over my K-slice (2 gates) from VGPR weights + LDS z
  auto matvec = [&](void) -> u64 {
    float a00=0.f,a01=0.f,a02=0.f,a03=0.f,a10=0.f,a11=0.f,a12=0.f,a13=0.f;
    const float4* z4 = (const float4*)z + sp*(kKs/4);
#pragma unroll
    for (int c = 0; c < kKs/4; ++c){
      float4 zz = z4[c];
      a00 += wreg[4*c+0]*zz.x; a01 += wreg[4*c+1]*zz.y;
      a02 += wreg[4*c+2]*zz.z; a03 += wreg[4*c+3]*zz.w;
      a10 += wreg[kKs+4*c+0]*zz.x; a11 += wreg[kKs+4*c+1]*zz.y;
      a12 += wreg[kKs+4*c+2]*zz.z; a13 += wreg[kKs+4*c+3]*zz.w;
    }
    float acc0 = (a00+a01)+(a02+a03);
    float acc1 = (a10+a11)+(a12+a13);
    return __builtin_bit_cast(u64, float2{acc0, acc1});
  };

  // publish my partial for `step` (release protocol proven in r6/r7)
  auto publishf = [&](int step, u64 val){
    const int par = step & 1;
    __hip_atomic_store(pbuf2 + (((size_t)par*kSp + sp)*kB + b)*512 + tid, val,
                       __ATOMIC_RELAXED, __HIP_MEMORY_SCOPE_AGENT);
    asm volatile("s_waitcnt vmcnt(0)" ::: "memory");
    __syncthreads();
    if (tid == 0)
      __hip_atomic_store(&flags[(par*kSp + sp)*kB + b], (unsigned)(step + 1),
                         __ATOMIC_RELEASE, __HIP_MEMORY_SCOPE_AGENT);
  };

  // prologue: partial_0 from z_0
  u64 mine = matvec();
  publishf(0, mine);

  for (int t = 0; t < kT; ++t){
    const int par = t & 1;
    const unsigned want = (unsigned)(t + 1);

    // prefetch x-part gates while polling (same for all sibling blocks)
    float4 gx = *(const float4*)(gatesXp + (((size_t)t*kB + b)*256 + j)*4);

    if (tid < kSp - 1){                      // 7 pollers, one per partner
      int s2p = tid < sp ? tid : tid + 1;
      unsigned int* fl = &flags[(par*kSp + s2p)*kB + b];
      while (__hip_atomic_load(fl, __ATOMIC_ACQUIRE, __HIP_MEMORY_SCOPE_AGENT) < want){}
    }
    __syncthreads();                         // partners' partials visible

    u64 pv[kSp];
#pragma unroll
    for (int s2 = 0; s2 < kSp; ++s2){
      if (s2 != sp)
        pv[s2] = __hip_atomic_load(pbuf2 + (((size_t)par*kSp + s2)*kB + b)*512 + tid,
                                   __ATOMIC_RELAXED, __HIP_MEMORY_SCOPE_AGENT);
    }
#pragma unroll
    for (int s2 = 0; s2 < kSp; ++s2) if (s2 == sp) pv[s2] = mine;

    // uniform order sum -> bitwise-identical gates in all sibling blocks
    float g0 = gp ? gx.z : gx.x;
    float g1 = gp ? gx.w : gx.y;
#pragma unroll
    for (int s2 = 0; s2 < kSp; ++s2){
      float2 pp = __builtin_bit_cast(float2, pv[s2]);
      g0 += pp.x; g1 += pp.y;
    }
    if (gp){ gbuf[0][j] = g0; gbuf[1][j] = g1; }
    __syncthreads();                         // A: full gates ready

    // LSTM cell (threads 0..255), identical in every sibling block
    if (tid < kH){
      float ig = sigf(g0);                   // gate i
      float fg = sigf(g1);                   // gate f
      float g2 = tanhf_fast(gbuf[0][j]);     // gate g
      float og = sigf(gbuf[1][j]);           // gate o
      float cn = fg*cst[j] + ig*g2;
      cst[j] = cn;
      float hn = og*tanhf_fast(cn);
      z[j] = hn;
      if (t >= kTenc && sp == 0)
        Hdec[(((size_t)(t - kTenc))*kB + b)*kH + j] = hn;
    }
    __syncthreads();                         // B: h ready

    if (t + 1 == kTenc){                     // switch to decoder weights
      const float* wb = wblob + ((size_t)(kSp + sp)*kWR)*512 + tid;
#pragma unroll
      for (int i = 0; i < kWR; ++i) wreg[i] = wb[(size_t)i*512];
#pragma unroll
      for (int i = 0; i < kWR; ++i) asm volatile("" : "+v"(wreg[i]));
    }
    if (t == kT - 1) break;

    if (sp != kSp - 1){
      // pure-h split: publish next partial immediately (overlaps stack work)
      mine = matvec();
      publishf(t + 1, mine);
    } else {
      // stack owner: controller + stack + r, then matvec + publish
      const int cnt = t + 1;
      if (wave == 0){
        const float* Wdu = (lane < 32) ? Wd : Wu;
        const int kl = lane & 31;
        float p = 0.f;
#pragma unroll
        for (int q2 = 0; q2 < 8; ++q2) p += z[kl + 32*q2] * Wdu[kl + 32*q2];
        p += swz<0x401F>(p); p += swz<0x201F>(p); p += swz<0x101F>(p);
        p += swz<0x081F>(p); p += swz<0x041F>(p);
        float o  = __shfl_xor(p, 32);
        float dd = sigf(((lane < 32) ? p : o) + bd[0]);
        float uu = sigf(((lane < 32) ? o : p) + bu[0]);

        float sm[5], sn[5];
        float csum = 0.f;
#pragma unroll
        for (int qq = 0; qq < 5; ++qq){
          int i = lane*5 + qq;
          float sv = (i < cnt) ? sbuf[i] : 0.f;
          sm[qq] = sv; csum += sv;
        }
        float run = wave_suffix_incl(csum, lane) - csum;
        float csum2 = 0.f;
#pragma unroll
        for (int qq = 4; qq >= 0; --qq){
          int i = lane*5 + qq;
          float sv;
          if (i == cnt)      sv = dd;
          else if (i < cnt)  sv = fmaxf(sm[qq] - fmaxf(uu - run, 0.f), 0.f);
          else               sv = 0.f;
          sn[qq] = sv;
          run  += sm[qq];
          csum2 += sv;
        }
#pragma unroll
        for (int qq = 0; qq < 5; ++qq){
          int i = lane*5 + qq;
          if (i < kCap) sbuf[i] = sn[qq];
        }
        float run2 = wave_suffix_incl(csum2, lane) - csum2;
#pragma unroll
        for (int qq = 4; qq >= 0; --qq){
          int i = lane*5 + qq;
          float cf = fminf(sn[qq], fmaxf(1.f - run2, 0.f));
          if (i < kCap) coeff[i] = cf;
          run2 += sn[qq];
        }
      } else if (tid >= 256){
        const int m = (tid - 256) >> 3, l = tid & 7;
        float p = 0.f;
        for (int k2 = l; k2 < kH; k2 += 8) p += z[k2] * Wv[m*kH + k2];
        p += swz<0x101F>(p); p += swz<0x081F>(p); p += swz<0x041F>(p);
        if (l == 0) Vbuf[cnt*kVs + m] = tanhf_fast(p + bv[m]);
      }
      __syncthreads();                       // D: coeff + Vbuf[cnt] ready

      if (tid < kH){                         // r[m] = sum_i coeff[i]*Vbuf[i][m]
        const int m = tid >> 3, l = tid & 7;
        float p = 0.f;
        for (int i = l; i <= cnt; i += 8) p += coeff[i]*Vbuf[i*kVs + m];
        p += swz<0x101F>(p); p += swz<0x081F>(p); p += swz<0x041F>(p);
        if (l == 0) z[kH + m] = p;
      }
      __syncthreads();                       // E: z (incl. r) ready

      mine = matvec();
      publishf(t + 1, mine);
    }
  }
}

// oc = tanh(h@Wo^T + bo); out = log_softmax(oc@Wlin^T + blin)
__global__ void k_out(const float* __restrict__ Hdec,
                      const float* __restrict__ WoT, const float* __restrict__ bo,
                      const float* __restrict__ WlinT, const float* __restrict__ blin,
                      float* __restrict__ out){
  const int row = blockIdx.x;
  const int tid = threadIdx.x;
  __shared__ float hr[kH], oc[kH], lg[kOut], st[2];
  hr[tid] = Hdec[(size_t)row*kH + tid];
  __syncthreads();
  float a = bo[tid];
  for (int k = 0; k < kH; ++k) a += hr[k]*WoT[k*kH + tid];
  oc[tid] = tanhf(a);
  __syncthreads();
  if (tid < kOut){
    float a2 = blin[tid];
    for (int k = 0; k < kH; ++k) a2 += oc[k]*WlinT[k*kOut + tid];
    lg[tid] = a2;
  }
  __syncthreads();
  if (tid < 64){
    float mx = -3.4e38f;
    for (int i = tid; i < kOut; i += 64) mx = fmaxf(mx, lg[i]);
#pragma unroll
    for (int off = 32; off; off >>= 1) mx = fmaxf(mx, __shfl_down(mx, off));
    mx = __shfl(mx, 0);
    float se = 0.f;
    for (int i = tid; i < kOut; i += 64) se += expf(lg[i] - mx);
#pragma unroll
    for (int off = 32; off; off >>= 1) se += __shfl_down(se, off);
    if (tid == 0){ st[0] = mx; st[1] = logf(se); }
  }
  __syncthreads();
  if (tid < kOut) out[(size_t)row*kOut + tid] = lg[tid] - st[0] - st[1];
}

extern "C" void kernel_launch(void* const* d_in, const int* in_sizes, int n_in,
                              void* d_out, int out_size, void* d_ws, size_t ws_size,
                              hipStream_t stream){
  (void)in_sizes; (void)n_in; (void)out_size; (void)ws_size;
  const float* X     = (const float*)d_in[0];
  const float* Y     = (const float*)d_in[1];
  const float* Wih_e = (const float*)d_in[2];
  const float* Whh_e = (const float*)d_in[3];
  const float* bih_e = (const float*)d_in[4];
  const float* bhh_e = (const float*)d_in[5];
  const float* Wih_d = (const float*)d_in[6];
  const float* Whh_d = (const float*)d_in[7];
  const float* bih_d = (const float*)d_in[8];
  const float* bhh_d = (const float*)d_in[9];
  const float* Wd    = (const float*)d_in[10];
  const float* bd    = (const float*)d_in[11];
  const float* Wu    = (const float*)d_in[12];
  const float* bu    = (const float*)d_in[13];
  const float* Wv    = (const float*)d_in[14];
  const float* bv    = (const float*)d_in[15];
  const float* Wo    = (const float*)d_in[16];
  const float* bo    = (const float*)d_in[17];
  const float* Wlin  = (const float*)d_in[18];
  const float* blin  = (const float*)d_in[19];
  const float* h0    = (const float*)d_in[20];
  const float* c0    = (const float*)d_in[21];
  float* out = (float*)d_out;

  float* ws = (float*)d_ws;
  size_t o = 0;
  float* gatesXp = ws + o; o += (size_t)kT*kB*kG;        // 8,388,608
  float* WixT_e  = ws + o; o += (size_t)kIn*kG;
  float* WixT_d  = ws + o; o += (size_t)kIn*kG;
  float* WoT     = ws + o; o += (size_t)kH*kH;
  float* WlinT   = ws + o; o += (size_t)kH*kOut;
  float* Hdec    = ws + o; o += (size_t)128*kB*kH;       // 1,048,576
  float* wblob   = ws + o; o += (size_t)2*kSp*kWR*512;   // 589,824
  u64*   pbuf2   = (u64*)(ws + o); o += (size_t)2*kSp*kB*512*2;  // 2 MB
  unsigned int* flags = (unsigned int*)(ws + o); o += 512; // 2*8*32 uints

  // flags must start at 0 every launch (harness re-poisons ws to 0xAA)
  hipMemsetAsync(flags, 0, 2*kSp*kB*sizeof(unsigned int), stream);

  auto tr = [&](float* dst, const float* src, int R, int C, int stride, int col0){
    int n = R*C;
    k_transpose<<<(n+255)/256, 256, 0, stream>>>(dst, src, R, C, stride, col0);
  };
  tr(WixT_e, Wih_e, kG, kIn, kIn+kM, 0);
  tr(WixT_d, Wih_d, kG, kIn, kIn+kM, 0);
  tr(WoT,   Wo,   kH,  kH, kH, 0);
  tr(WlinT, Wlin, kOut, kH, kH, 0);

  const int npack = kSp*kWR*512;
  k_packw<<<(npack+255)/256, 256, 0, stream>>>(wblob,                 Wih_e, Whh_e);
  k_packw<<<(npack+255)/256, 256, 0, stream>>>(wblob + (size_t)npack, Wih_d, Whh_d);

  k_gatesx<<<dim3(kT,4), 256, 0, stream>>>(X, Y, WixT_e, WixT_d,
                                           bih_e, bhh_e, bih_d, bhh_d, gatesXp);
  k_seq<<<kB*kSp, 512, 0, stream>>>(gatesXp, wblob, pbuf2, flags,
                                    Wd, bd, Wu, bu, Wv, bv, h0, c0, Hdec);
  k_out<<<128*kB, 256, 0, stream>>>(Hdec, WoT, bo, WlinT, blin, out);
}

// Round 10
// 1750.229 us; speedup vs baseline: 1.9350x; 1.9350x over previous
//
#include <hip/hip_runtime.h>
#include <math.h>

typedef unsigned long long u64;

namespace {
constexpr int kH    = 256;   // hidden
constexpr int kM    = 32;    // stack value dim
constexpr int kIn   = 131;   // input dim
constexpr int kOut  = 131;   // output dim
constexpr int kB    = 32;    // batch
constexpr int kTenc = 128;   // encoder steps
constexpr int kT    = 256;   // total sequential steps
constexpr int kCap  = 257;   // stack capacity
constexpr int kG    = 1024;  // 4*H gates
constexpr int kK    = 288;   // H + M combined recurrent input
constexpr int kSp   = 8;     // column-split: blocks per batch, each owns 32 j's x 4 gates
constexpr int kSl   = 32;    // j-slice per block
constexpr int kKq   = 72;    // K elems per thread (4 threads per column)
constexpr int kWR   = 72;    // fp32 weights per thread, VGPR-resident (fits 128-class)
constexpr int kVs   = 36;    // Vbuf row stride
}

__device__ __forceinline__ float frcp(float x){ return __builtin_amdgcn_rcpf(x); }
__device__ __forceinline__ float sigf(float x){ return frcp(1.0f + __expf(-x)); }
__device__ __forceinline__ float tanhf_fast(float x){
  return 1.0f - 2.0f*frcp(__expf(2.0f*x) + 1.0f);   // saturates via inf/0
}

template<int PAT>
__device__ __forceinline__ float swz(float x){
  return __int_as_float(__builtin_amdgcn_ds_swizzle(__float_as_int(x), PAT));
}

// dst[c*R + r] = src[r*stride + col0 + c]
__global__ void k_transpose(float* __restrict__ dst, const float* __restrict__ src,
                            int R, int C, int stride, int col0){
  int idx = blockIdx.x*256 + threadIdx.x;
  if (idx >= R*C) return;
  int rr = idx / C;
  int cc = idx - rr*C;
  dst[cc*R + rr] = src[rr*stride + col0 + cc];
}

// Column-split weight pack: dst[(sp*kWR + i)*512 + tid]
//   thread tid: lc = tid&127 (local column), q = tid>>7 (K-quarter)
//   col = (lc>>5)*256 + sp*32 + (lc&31)   (gate type g = lc>>5, unit j = sp*32+(lc&31))
//   k = q*72 + i ; k<256 -> Whh[col][k], else Wih[col][131 + (k-256)]
__global__ void k_packw(float* __restrict__ dst, const float* __restrict__ Wih,
                        const float* __restrict__ Whh){
  int idx = blockIdx.x*256 + threadIdx.x;
  if (idx >= kSp*kWR*512) return;
  int tid  = idx & 511;
  int rest = idx >> 9;             // sp*kWR + i
  int sp = rest / kWR, i = rest - sp*kWR;
  int lc = tid & 127, q = tid >> 7;
  int col = (lc >> 5)*256 + sp*kSl + (lc & 31);
  int k   = q*kKq + i;
  dst[idx] = (k < kH) ? Whh[col*kH + k] : Wih[col*(kIn+kM) + kIn + (k - kH)];
}

// gatesXp[t][b][j][g] = sum_k x_t[b][k]*Wih[g*256+j][k] + bih + bhh
__global__ void k_gatesx(const float* __restrict__ X, const float* __restrict__ Y,
                         const float* __restrict__ WixT_e, const float* __restrict__ WixT_d,
                         const float* __restrict__ bih_e, const float* __restrict__ bhh_e,
                         const float* __restrict__ bih_d, const float* __restrict__ bhh_d,
                         float* __restrict__ gatesXp){
  const int t   = blockIdx.x;
  const int col = blockIdx.y*256 + threadIdx.x;
  __shared__ float xl[kB*kIn];
  const float* xsrc;
  if (t < kTenc)       xsrc = X + (size_t)t*kB*kIn;
  else if (t == kTenc) xsrc = X + (size_t)kTenc*kB*kIn;
  else                 xsrc = Y + (size_t)(t-kTenc-1)*kB*kIn;
  for (int i = threadIdx.x; i < kB*kIn; i += 256) xl[i] = xsrc[i];
  __syncthreads();
  const float* WT   = (t < kTenc) ? WixT_e : WixT_d;
  const float  bias = (t < kTenc) ? (bih_e[col] + bhh_e[col]) : (bih_d[col] + bhh_d[col]);
  float acc[kB];
#pragma unroll
  for (int b = 0; b < kB; ++b) acc[b] = bias;
  for (int k = 0; k < kIn; ++k){
    float wk = WT[k*kG + col];
#pragma unroll
    for (int b = 0; b < kB; ++b) acc[b] += wk * xl[b*kIn + k];
  }
  const int j = col & 255, g = col >> 8;
#pragma unroll
  for (int b = 0; b < kB; ++b)
    gatesXp[(((size_t)t*kB + b)*256 + j)*4 + g] = acc[b];
}

__device__ __forceinline__ float wave_suffix_incl(float x, int lane){
#pragma unroll
  for (int off = 1; off < 64; off <<= 1){
    float t = __shfl_down(x, off);
    if (lane + off < 64) x += t;
  }
  return x;
}

__global__ void __launch_bounds__(512, 1)
k_seq(const float* __restrict__ gatesXp, const float* __restrict__ wblob,
      u64* __restrict__ hbuf,
      const float* __restrict__ Wd, const float* __restrict__ bd,
      const float* __restrict__ Wu, const float* __restrict__ bu,
      const float* __restrict__ Wv, const float* __restrict__ bv,
      const float* __restrict__ h0, const float* __restrict__ c0,
      float* __restrict__ Hdec){
  const int bid  = blockIdx.x;
  const int b    = bid >> 3;       // batch element
  const int sp   = bid & 7;        // column-split id (owns j in [sp*32, sp*32+32))
  const int tid  = threadIdx.x;
  const int lane = tid & 63;
  const int wave = tid >> 6;
  const int lc   = tid & 127;      // local column
  const int q    = tid >> 7;       // K-quarter

  __shared__ __align__(16) float z[kK];   // [h(256) | r(32)] — full recurrent state
  __shared__ float cst[kSl];              // c for OWN j-slice only
  __shared__ float red[512];              // matvec partials [q*128 + lc]
  __shared__ float sbuf[kCap];            // stack strengths (redundant, identical)
  __shared__ float coeff[kCap];
  __shared__ float Vbuf[kCap*kVs];

  if (tid < kH) z[tid] = h0[tid];
  if (tid >= kH && tid < kK) z[tid] = 0.f;
  if (tid < kSl) cst[tid] = c0[sp*kSl + tid];
  for (int i = tid; i < kCap; i += 512) sbuf[i] = 0.f;
  if (tid < kVs) Vbuf[tid] = 0.f;         // row 0 (never written, coeff=0)
  __syncthreads();

  float wreg[kWR];
  {
    const float* wb = wblob + ((size_t)sp*kWR)*512 + tid;   // encoder slice
#pragma unroll
    for (int i = 0; i < kWR; ++i) wreg[i] = wb[(size_t)i*512];
#pragma unroll
    for (int i = 0; i < kWR; ++i) asm volatile("" : "+v"(wreg[i]));
  }

  for (int t = 0; t < kT; ++t){
    // prefetch x-part gates for own slice (tid<32): float4 = (i,f,g,o) of unit sp*32+tid
    float4 gx = {0.f,0.f,0.f,0.f};
    if (tid < kSl)
      gx = *(const float4*)(gatesXp + (((size_t)t*kB + b)*256 + sp*kSl + tid)*4);

    // ---- matvec: one column per thread over K-quarter q (72 FMA, VGPR weights)
    {
      float a0=0.f,a1=0.f,a2=0.f,a3=0.f;
      const float4* z4 = (const float4*)z + q*(kKq/4);
#pragma unroll
      for (int c = 0; c < kKq/4; ++c){
        float4 zz = z4[c];
        a0 += wreg[4*c+0]*zz.x; a1 += wreg[4*c+1]*zz.y;
        a2 += wreg[4*c+2]*zz.z; a3 += wreg[4*c+3]*zz.w;
      }
      red[tid] = (a0+a1)+(a2+a3);
    }
    __syncthreads();                       // red ready

    // ---- cell + publish (tid<32): sum 4 quarters x 4 gate types, LSTM, broadcast h
    if (tid < kSl){
      float gi = gx.x + ((red[tid      ] + red[tid+128+  0]) + (red[tid+256+  0] + red[tid+384+  0]));
      // lc for gate g is g*32+tid; red index = q*128 + lc
      float gf = gx.y + ((red[ 32+tid] + red[160+tid]) + (red[288+tid] + red[416+tid]));
      float gg = gx.z + ((red[ 64+tid] + red[192+tid]) + (red[320+tid] + red[448+tid]));
      float go = gx.w + ((red[ 96+tid] + red[224+tid]) + (red[352+tid] + red[480+tid]));
      float ig = sigf(gi), fg = sigf(gf), g2 = tanhf_fast(gg), og = sigf(go);
      float cn = fg*cst[tid] + ig*g2;
      cst[tid] = cn;
      float hn = og*tanhf_fast(cn);
      const int j = sp*kSl + tid;
      z[j] = hn;                            // own slice into LDS state
      // publish (tag | h) as one atomic u64 — parity-2 ring, tag = t
      u64 pk = ((u64)(unsigned)t << 32) | (u64)__float_as_uint(hn);
      __hip_atomic_store(hbuf + ((size_t)(t & 1)*kB + b)*kH + j, pk,
                         __ATOMIC_RELAXED, __HIP_MEMORY_SCOPE_AGENT);
      if (t >= kTenc)
        Hdec[(((size_t)(t - kTenc))*kB + b)*kH + j] = hn;
    }
    if (t == kT - 1) break;

    if (t + 1 == kTenc){                    // switch to decoder weights (overlaps gather)
      const float* wb = wblob + ((size_t)(kSp + sp)*kWR)*512 + tid;
#pragma unroll
      for (int i = 0; i < kWR; ++i) wreg[i] = wb[(size_t)i*512];
#pragma unroll
      for (int i = 0; i < kWR; ++i) asm volatile("" : "+v"(wreg[i]));
    }

    // ---- gather partners' h-slices: poll directly on (tag|value) u64s
    if (tid < (kSp-1)*kSl){                 // 224 threads, one element each
      int p  = tid >> 5;                    // partner ordinal 0..6
      int sp2 = p + (p >= sp);              // skip self
      int j  = sp2*kSl + (tid & 31);
      const u64* src = hbuf + ((size_t)(t & 1)*kB + b)*kH + j;
      u64 v;
      do {
        v = __hip_atomic_load(src, __ATOMIC_RELAXED, __HIP_MEMORY_SCOPE_AGENT);
      } while ((unsigned)(v >> 32) != (unsigned)t);
      z[j] = __uint_as_float((unsigned)v);
    }
    __syncthreads();                        // full h_t in z

    // ---- stack phases (redundant in every block, identical inputs -> identical r)
    const int cnt = t + 1;
    if (wave == 0){
      const float* Wdu = (lane < 32) ? Wd : Wu;
      const int kl = lane & 31;
      float p = 0.f;
#pragma unroll
      for (int q2 = 0; q2 < 8; ++q2) p += z[kl + 32*q2] * Wdu[kl + 32*q2];
      p += swz<0x401F>(p); p += swz<0x201F>(p); p += swz<0x101F>(p);
      p += swz<0x081F>(p); p += swz<0x041F>(p);
      float o  = __shfl_xor(p, 32);
      float dd = sigf(((lane < 32) ? p : o) + bd[0]);
      float uu = sigf(((lane < 32) ? o : p) + bu[0]);

      float sm[5], sn[5];
      float csum = 0.f;
#pragma unroll
      for (int qq = 0; qq < 5; ++qq){
        int i = lane*5 + qq;
        float sv = (i < cnt) ? sbuf[i] : 0.f;
        sm[qq] = sv; csum += sv;
      }
      float run = wave_suffix_incl(csum, lane) - csum;
      float csum2 = 0.f;
#pragma unroll
      for (int qq = 4; qq >= 0; --qq){
        int i = lane*5 + qq;
        float sv;
        if (i == cnt)      sv = dd;
        else if (i < cnt)  sv = fmaxf(sm[qq] - fmaxf(uu - run, 0.f), 0.f);
        else               sv = 0.f;
        sn[qq] = sv;
        run  += sm[qq];
        csum2 += sv;
      }
#pragma unroll
      for (int qq = 0; qq < 5; ++qq){
        int i = lane*5 + qq;
        if (i < kCap) sbuf[i] = sn[qq];
      }
      float run2 = wave_suffix_incl(csum2, lane) - csum2;
#pragma unroll
      for (int qq = 4; qq >= 0; --qq){
        int i = lane*5 + qq;
        float cf = fminf(sn[qq], fmaxf(1.f - run2, 0.f));
        if (i < kCap) coeff[i] = cf;
        run2 += sn[qq];
      }
    } else if (tid >= 256){
      const int m = (tid - 256) >> 3, l = tid & 7;
      float p = 0.f;
      for (int k2 = l; k2 < kH; k2 += 8) p += z[k2] * Wv[m*kH + k2];
      p += swz<0x101F>(p); p += swz<0x081F>(p); p += swz<0x041F>(p);
      if (l == 0) Vbuf[cnt*kVs + m] = tanhf_fast(p + bv[m]);
    }
    __syncthreads();                        // coeff + Vbuf[cnt] ready

    if (tid < kH){                          // r[m] = sum_i coeff[i]*Vbuf[i][m]
      const int m = tid >> 3, l = tid & 7;
      float p = 0.f;
      for (int i = l; i <= cnt; i += 8) p += coeff[i]*Vbuf[i*kVs + m];
      p += swz<0x101F>(p); p += swz<0x081F>(p); p += swz<0x041F>(p);
      if (l == 0) z[kH + m] = p;
    }
    __syncthreads();                        // z = [h_t | r_t] ready for next matvec
  }
}

// oc = tanh(h@Wo^T + bo); out = log_softmax(oc@Wlin^T + blin)
__global__ void k_out(const float* __restrict__ Hdec,
                      const float* __restrict__ WoT, const float* __restrict__ bo,
                      const float* __restrict__ WlinT, const float* __restrict__ blin,
                      float* __restrict__ out){
  const int row = blockIdx.x;
  const int tid = threadIdx.x;
  __shared__ float hr[kH], oc[kH], lg[kOut], st[2];
  hr[tid] = Hdec[(size_t)row*kH + tid];
  __syncthreads();
  float a = bo[tid];
  for (int k = 0; k < kH; ++k) a += hr[k]*WoT[k*kH + tid];
  oc[tid] = tanhf(a);
  __syncthreads();
  if (tid < kOut){
    float a2 = blin[tid];
    for (int k = 0; k < kH; ++k) a2 += oc[k]*WlinT[k*kOut + tid];
    lg[tid] = a2;
  }
  __syncthreads();
  if (tid < 64){
    float mx = -3.4e38f;
    for (int i = tid; i < kOut; i += 64) mx = fmaxf(mx, lg[i]);
#pragma unroll
    for (int off = 32; off; off >>= 1) mx = fmaxf(mx, __shfl_down(mx, off));
    mx = __shfl(mx, 0);
    float se = 0.f;
    for (int i = tid; i < kOut; i += 64) se += expf(lg[i] - mx);
#pragma unroll
    for (int off = 32; off; off >>= 1) se += __shfl_down(se, off);
    if (tid == 0){ st[0] = mx; st[1] = logf(se); }
  }
  __syncthreads();
  if (tid < kOut) out[(size_t)row*kOut + tid] = lg[tid] - st[0] - st[1];
}

extern "C" void kernel_launch(void* const* d_in, const int* in_sizes, int n_in,
                              void* d_out, int out_size, void* d_ws, size_t ws_size,
                              hipStream_t stream){
  (void)in_sizes; (void)n_in; (void)out_size; (void)ws_size;
  const float* X     = (const float*)d_in[0];
  const float* Y     = (const float*)d_in[1];
  const float* Wih_e = (const float*)d_in[2];
  const float* Whh_e = (const float*)d_in[3];
  const float* bih_e = (const float*)d_in[4];
  const float* bhh_e = (const float*)d_in[5];
  const float* Wih_d = (const float*)d_in[6];
  const float* Whh_d = (const float*)d_in[7];
  const float* bih_d = (const float*)d_in[8];
  const float* bhh_d = (const float*)d_in[9];
  const float* Wd    = (const float*)d_in[10];
  const float* bd    = (const float*)d_in[11];
  const float* Wu    = (const float*)d_in[12];
  const float* bu    = (const float*)d_in[13];
  const float* Wv    = (const float*)d_in[14];
  const float* bv    = (const float*)d_in[15];
  const float* Wo    = (const float*)d_in[16];
  const float* bo    = (const float*)d_in[17];
  const float* Wlin  = (const float*)d_in[18];
  const float* blin  = (const float*)d_in[19];
  const float* h0    = (const float*)d_in[20];
  const float* c0    = (const float*)d_in[21];
  float* out = (float*)d_out;

  float* ws = (float*)d_ws;
  size_t o = 0;
  float* gatesXp = ws + o; o += (size_t)kT*kB*kG;        // 8,388,608
  float* WixT_e  = ws + o; o += (size_t)kIn*kG;
  float* WixT_d  = ws + o; o += (size_t)kIn*kG;
  float* WoT     = ws + o; o += (size_t)kH*kH;
  float* WlinT   = ws + o; o += (size_t)kH*kOut;
  float* Hdec    = ws + o; o += (size_t)128*kB*kH;       // 1,048,576
  float* wblob   = ws + o; o += (size_t)2*kSp*kWR*512;   // 589,824
  u64*   hbuf    = (u64*)(ws + o); o += (size_t)2*2*kB*kH; // 2 slots x 32 x 256 u64
  // tags in hbuf are compared by equality to t in [0,256); the harness's 0xAA
  // poison gives tag 0xAAAAAAAA which never matches -> no memset needed.

  auto tr = [&](float* dst, const float* src, int R, int C, int stride, int col0){
    int n = R*C;
    k_transpose<<<(n+255)/256, 256, 0, stream>>>(dst, src, R, C, stride, col0);
  };
  tr(WixT_e, Wih_e, kG, kIn, kIn+kM, 0);
  tr(WixT_d, Wih_d, kG, kIn, kIn+kM, 0);
  tr(WoT,   Wo,   kH,  kH, kH, 0);
  tr(WlinT, Wlin, kOut, kH, kH, 0);

  const int npack = kSp*kWR*512;
  k_packw<<<(npack+255)/256, 256, 0, stream>>>(wblob,                 Wih_e, Whh_e);
  k_packw<<<(npack+255)/256, 256, 0, stream>>>(wblob + (size_t)npack, Wih_d, Whh_d);

  k_gatesx<<<dim3(kT,4), 256, 0, stream>>>(X, Y, WixT_e, WixT_d,
                                           bih_e, bhh_e, bih_d, bhh_d, gatesXp);
  k_seq<<<kB*kSp, 512, 0, stream>>>(gatesXp, wblob, hbuf,
                                    Wd, bd, Wu, bu, Wv, bv, h0, c0, Hdec);
  k_out<<<128*kB, 256, 0, stream>>>(Hdec, WoT, bo, WlinT, blin, out);
}

// Round 11
// 1739.729 us; speedup vs baseline: 1.9467x; 1.0060x over previous
//
#include <hip/hip_runtime.h>
#include <math.h>

typedef unsigned long long u64;

namespace {
constexpr int kH    = 256;   // hidden
constexpr int kM    = 32;    // stack value dim
constexpr int kIn   = 131;   // input dim
constexpr int kOut  = 131;   // output dim
constexpr int kB    = 32;    // batch
constexpr int kTenc = 128;   // encoder steps
constexpr int kT    = 256;   // total sequential steps
constexpr int kCap  = 257;   // stack capacity
constexpr int kG    = 1024;  // 4*H gates
constexpr int kSp   = 8;     // column-split blocks per batch (32 units each)
constexpr int kSl   = 32;    // units per block
constexpr int kWR   = 72;    // fp32 weights/thread: 64 h-K + 8 r-K (128-VGPR class)
constexpr int kVs   = 36;    // Vbuf row stride
constexpr int kWvS  = 33;    // WvL row stride (bank-spread)
}

__device__ __forceinline__ float frcp(float x){ return __builtin_amdgcn_rcpf(x); }
__device__ __forceinline__ float sigf(float x){ return frcp(1.0f + __expf(-x)); }
__device__ __forceinline__ float tanhf_fast(float x){
  return 1.0f - 2.0f*frcp(__expf(2.0f*x) + 1.0f);   // saturates via inf/0
}

template<int PAT>
__device__ __forceinline__ float swz(float x){
  return __int_as_float(__builtin_amdgcn_ds_swizzle(__float_as_int(x), PAT));
}

// dst[c*R + r] = src[r*stride + col0 + c]
__global__ void k_transpose(float* __restrict__ dst, const float* __restrict__ src,
                            int R, int C, int stride, int col0){
  int idx = blockIdx.x*256 + threadIdx.x;
  if (idx >= R*C) return;
  int rr = idx / C;
  int cc = idx - rr*C;
  dst[cc*R + rr] = src[rr*stride + col0 + cc];
}

// Weight pack for in-wave-cell k_seq.
// thread tid: uj=tid>>4, g=(tid>>2)&3, q=tid&3; col = g*256 + sp*32 + uj
// i<64: k = q*64+i (h-part) ; i>=64: k = 256 + q*8 + (i-64) (r-part)
__global__ void k_packw(float* __restrict__ dst, const float* __restrict__ Wih,
                        const float* __restrict__ Whh){
  int idx = blockIdx.x*256 + threadIdx.x;
  if (idx >= kSp*kWR*512) return;
  int tid  = idx & 511;
  int rest = idx >> 9;             // sp*kWR + i
  int sp = rest / kWR, i = rest - sp*kWR;
  int uj = tid >> 4, g = (tid >> 2) & 3, q = tid & 3;
  int col = g*256 + sp*kSl + uj;
  int k   = (i < 64) ? (q*64 + i) : (256 + q*8 + (i - 64));
  dst[idx] = (k < kH) ? Whh[col*kH + k] : Wih[col*(kIn+kM) + kIn + (k - kH)];
}

// gatesXp[t][b][j][g] = sum_k x_t[b][k]*Wih[g*256+j][k] + bih + bhh
__global__ void k_gatesx(const float* __restrict__ X, const float* __restrict__ Y,
                         const float* __restrict__ WixT_e, const float* __restrict__ WixT_d,
                         const float* __restrict__ bih_e, const float* __restrict__ bhh_e,
                         const float* __restrict__ bih_d, const float* __restrict__ bhh_d,
                         float* __restrict__ gatesXp){
  const int t   = blockIdx.x;
  const int col = blockIdx.y*256 + threadIdx.x;
  __shared__ float xl[kB*kIn];
  const float* xsrc;
  if (t < kTenc)       xsrc = X + (size_t)t*kB*kIn;
  else if (t == kTenc) xsrc = X + (size_t)kTenc*kB*kIn;
  else                 xsrc = Y + (size_t)(t-kTenc-1)*kB*kIn;
  for (int i = threadIdx.x; i < kB*kIn; i += 256) xl[i] = xsrc[i];
  __syncthreads();
  const float* WT   = (t < kTenc) ? WixT_e : WixT_d;
  const float  bias = (t < kTenc) ? (bih_e[col] + bhh_e[col]) : (bih_d[col] + bhh_d[col]);
  float acc[kB];
#pragma unroll
  for (int b = 0; b < kB; ++b) acc[b] = bias;
  for (int k = 0; k < kIn; ++k){
    float wk = WT[k*kG + col];
#pragma unroll
    for (int b = 0; b < kB; ++b) acc[b] += wk * xl[b*kIn + k];
  }
  const int j = col & 255, g = col >> 8;
#pragma unroll
  for (int b = 0; b < kB; ++b)
    gatesXp[(((size_t)t*kB + b)*256 + j)*4 + g] = acc[b];
}

__device__ __forceinline__ float wave_suffix_incl(float x, int lane){
#pragma unroll
  for (int off = 1; off < 64; off <<= 1){
    float t = __shfl_down(x, off);
    if (lane + off < 64) x += t;
  }
  return x;
}

__global__ void __launch_bounds__(512, 1)
k_seq(const float* __restrict__ gatesXp, const float* __restrict__ wblob,
      u64* __restrict__ hbuf,
      const float* __restrict__ Wd, const float* __restrict__ bd,
      const float* __restrict__ Wu, const float* __restrict__ bu,
      const float* __restrict__ Wv, const float* __restrict__ bv,
      const float* __restrict__ h0, const float* __restrict__ c0,
      float* __restrict__ Hdec){
  const int bid  = blockIdx.x;
  const int b    = bid >> 3;       // batch element
  const int sp   = bid & 7;        // column-split id
  const int tid  = threadIdx.x;
  const int lane = tid & 63;
  const int wave = tid >> 6;
  const int uj   = tid >> 4;       // hidden unit 0..31 (16 lanes each, wave-contig)
  const int g    = (tid >> 2) & 3; // gate type
  const int q    = tid & 3;        // K-quarter

  __shared__ __align__(16) float z[kH + kM];   // [h | r]
  __shared__ float cst[kSl];
  __shared__ float sbuf[kCap];
  __shared__ float coeff[kCap];
  __shared__ float Vbuf[kCap*kVs];
  __shared__ float WvL[kH*kWvS];               // [k][m] stride 33
  __shared__ float WdL[kH], WuL[kH], bvL[kM];

  // ---- one-time staging
  if (tid < kH) z[tid] = h0[tid];
  if (tid >= kH && tid < kH+kM) z[tid] = 0.f;
  if (tid < kSl) cst[tid] = c0[sp*kSl + tid];
  for (int i = tid; i < kCap; i += 512) sbuf[i] = 0.f;
  if (tid < kVs) Vbuf[tid] = 0.f;              // row 0 stays zero (coeff[0]*0)
  for (int i = tid; i < kH*kM; i += 512){
    int k = i >> 5, m = i & 31;
    WvL[k*kWvS + m] = Wv[m*kH + k];
  }
  if (tid < kH){ WdL[tid] = Wd[tid]; WuL[tid] = Wu[tid]; }
  if (tid < kM) bvL[tid] = bv[tid];
  __syncthreads();

  float wreg[kWR];
  {
    const float* wb = wblob + ((size_t)sp*kWR)*512 + tid;   // encoder slice
#pragma unroll
    for (int i = 0; i < kWR; ++i) wreg[i] = wb[(size_t)i*512];
#pragma unroll
    for (int i = 0; i < kWR; ++i) asm volatile("" : "+v"(wreg[i]));
  }

  for (int t = 0; t < kT; ++t){
    // issue gx early (all 16 lanes of a unit load the same float4 -> coalesced)
    const float4 gx = *(const float4*)(gatesXp + (((size_t)t*kB + b)*256 + sp*kSl + uj)*4);

    // ---- gate matvec: h-main (64 K) + r-tail (8 K), pure VGPR weights + LDS z
    float acc;
    {
      float a0=0.f,a1=0.f,a2=0.f,a3=0.f;
      const float4* z4 = (const float4*)z;
#pragma unroll
      for (int c = 0; c < 16; ++c){
        float4 zz = z4[q*16 + c];
        a0 += wreg[4*c+0]*zz.x; a1 += wreg[4*c+1]*zz.y;
        a2 += wreg[4*c+2]*zz.z; a3 += wreg[4*c+3]*zz.w;
      }
      float4 t0 = z4[64 + 2*q], t1 = z4[64 + 2*q + 1];
      a0 += wreg[64]*t0.x + wreg[68]*t1.x;
      a1 += wreg[65]*t0.y + wreg[69]*t1.y;
      a2 += wreg[66]*t0.z + wreg[70]*t1.z;
      a3 += wreg[67]*t0.w + wreg[71]*t1.w;
      acc = (a0+a1)+(a2+a3);
    }
    // q-reduce within the 4 quarter-lanes (bits 0-1)
    acc += __shfl_xor(acc, 1);
    acc += __shfl_xor(acc, 2);
    // cross-gate exchange (bits 2-3): every lane gets all 4 gate sums
    float s4  = __shfl_xor(acc, 4);    // gate g^1
    float s8  = __shfl_xor(acc, 8);    // gate g^2
    float s12 = __shfl_xor(acc, 12);   // gate g^3
    float gi = (g==0)?acc:(g==1)?s4:(g==2)?s8:s12;
    float gf = (g==1)?acc:(g==0)?s4:(g==3)?s8:s12;
    float gg = (g==2)?acc:(g==3)?s4:(g==0)?s8:s12;
    float go = (g==3)?acc:(g==2)?s4:(g==1)?s8:s12;
    gi += gx.x; gf += gx.y; gg += gx.z; go += gx.w;

    // ---- LSTM cell (computed redundantly by all 16 lanes of the unit)
    float cold = cst[uj];
    float ig = sigf(gi), fg = sigf(gf), g2 = tanhf_fast(gg), og = sigf(go);
    float cn = fg*cold + ig*g2;
    float hn = og*tanhf_fast(cn);
    const int j = sp*kSl + uj;
    if ((tid & 15) == 0){
      cst[uj] = cn;
      z[j] = hn;
      __hip_atomic_store(hbuf + ((size_t)(t & 1)*kB + b)*kH + j,
                         ((u64)(unsigned)t << 32) | (u64)__float_as_uint(hn),
                         __ATOMIC_RELAXED, __HIP_MEMORY_SCOPE_AGENT);
      if (t >= kTenc)
        Hdec[(((size_t)(t - kTenc))*kB + b)*kH + j] = hn;
    }
    if (t == kT - 1) break;

    if (t + 1 == kTenc){                    // decoder weight reload (once)
      const float* wb = wblob + ((size_t)(kSp + sp)*kWR)*512 + tid;
#pragma unroll
      for (int i = 0; i < kWR; ++i) wreg[i] = wb[(size_t)i*512];
#pragma unroll
      for (int i = 0; i < kWR; ++i) asm volatile("" : "+v"(wreg[i]));
    }

    // ---- gather partners' h (224 pollers in waves 4.5-8)
    if (tid >= 288){
      int idx = tid - 288;                  // 0..223
      int p   = idx >> 5;
      int sp2 = p + (p >= sp);
      int jj  = sp2*kSl + (idx & 31);
      const u64* src = hbuf + ((size_t)(t & 1)*kB + b)*kH + jj;
      u64 v;
      do {
        v = __hip_atomic_load(src, __ATOMIC_RELAXED, __HIP_MEMORY_SCOPE_AGENT);
      } while ((unsigned)(v >> 32) != (unsigned)t);
      z[jj] = __uint_as_float((unsigned)v);
    }
    __syncthreads();                        // bar1: full h_t in z

    // ---- phase C: wave0 d/u + scan ; tid>=256 v (LDS weights)
    const int cnt = t + 1;
    if (wave == 0){
      const float* WduL = (lane < 32) ? WdL : WuL;
      const int kl = lane & 31;
      float p = 0.f;
#pragma unroll
      for (int s = 0; s < 8; ++s) p += z[kl + 32*s] * WduL[kl + 32*s];
      p += swz<0x401F>(p); p += swz<0x201F>(p); p += swz<0x101F>(p);
      p += swz<0x081F>(p); p += swz<0x041F>(p);
      float o  = __shfl_xor(p, 32);
      float dd = sigf(((lane < 32) ? p : o) + bd[0]);
      float uu = sigf(((lane < 32) ? o : p) + bu[0]);

      float sm[5], sn[5];
      float csum = 0.f;
#pragma unroll
      for (int qq = 0; qq < 5; ++qq){
        int i = lane*5 + qq;
        float sv = (i < cnt) ? sbuf[i] : 0.f;
        sm[qq] = sv; csum += sv;
      }
      float run = wave_suffix_incl(csum, lane) - csum;
      float csum2 = 0.f;
#pragma unroll
      for (int qq = 4; qq >= 0; --qq){
        int i = lane*5 + qq;
        float sv;
        if (i == cnt)      sv = dd;
        else if (i < cnt)  sv = fmaxf(sm[qq] - fmaxf(uu - run, 0.f), 0.f);
        else               sv = 0.f;
        sn[qq] = sv;
        run  += sm[qq];
        csum2 += sv;
      }
#pragma unroll
      for (int qq = 0; qq < 5; ++qq){
        int i = lane*5 + qq;
        if (i < kCap) sbuf[i] = sn[qq];
      }
      float run2 = wave_suffix_incl(csum2, lane) - csum2;
#pragma unroll
      for (int qq = 4; qq >= 0; --qq){
        int i = lane*5 + qq;
        float cf = fminf(sn[qq], fmaxf(1.f - run2, 0.f));
        if (i < kCap) coeff[i] = cf;
        run2 += sn[qq];
      }
    } else if (tid >= 256){
      const int m = (tid - 256) >> 3, l = tid & 7;
      float p = 0.f;
      for (int k2 = l; k2 < kH; k2 += 8) p += z[k2] * WvL[k2*kWvS + m];
      p += swz<0x101F>(p); p += swz<0x081F>(p); p += swz<0x041F>(p);
      if (l == 0) Vbuf[cnt*kVs + m] = tanhf_fast(p + bvL[m]);
    }
    __syncthreads();                        // barD: coeff + Vbuf[cnt] ready

    // ---- phase D: r-reduce on tid 64..191 (4 lanes per m)
    if (tid >= 64 && tid < 192){
      const int m = (tid - 64) >> 2, l = tid & 3;
      float p = 0.f;
      for (int i = l; i <= cnt; i += 4) p += coeff[i]*Vbuf[i*kVs + m];
      p += swz<0x041F>(p); p += swz<0x081F>(p);
      if (l == 0) z[kH + m] = p;
    }
    __syncthreads();                        // barE: z = [h_t | r_t] complete
  }
}

// oc = tanh(h@Wo^T + bo); out = log_softmax(oc@Wlin^T + blin)
__global__ void k_out(const float* __restrict__ Hdec,
                      const float* __restrict__ WoT, const float* __restrict__ bo,
                      const float* __restrict__ WlinT, const float* __restrict__ blin,
                      float* __restrict__ out){
  const int row = blockIdx.x;
  const int tid = threadIdx.x;
  __shared__ float hr[kH], oc[kH], lg[kOut], st[2];
  hr[tid] = Hdec[(size_t)row*kH + tid];
  __syncthreads();
  float a = bo[tid];
  for (int k = 0; k < kH; ++k) a += hr[k]*WoT[k*kH + tid];
  oc[tid] = tanhf(a);
  __syncthreads();
  if (tid < kOut){
    float a2 = blin[tid];
    for (int k = 0; k < kH; ++k) a2 += oc[k]*WlinT[k*kOut + tid];
    lg[tid] = a2;
  }
  __syncthreads();
  if (tid < 64){
    float mx = -3.4e38f;
    for (int i = tid; i < kOut; i += 64) mx = fmaxf(mx, lg[i]);
#pragma unroll
    for (int off = 32; off; off >>= 1) mx = fmaxf(mx, __shfl_down(mx, off));
    mx = __shfl(mx, 0);
    float se = 0.f;
    for (int i = tid; i < kOut; i += 64) se += expf(lg[i] - mx);
#pragma unroll
    for (int off = 32; off; off >>= 1) se += __shfl_down(se, off);
    if (tid == 0){ st[0] = mx; st[1] = logf(se); }
  }
  __syncthreads();
  if (tid < kOut) out[(size_t)row*kOut + tid] = lg[tid] - st[0] - st[1];
}

extern "C" void kernel_launch(void* const* d_in, const int* in_sizes, int n_in,
                              void* d_out, int out_size, void* d_ws, size_t ws_size,
                              hipStream_t stream){
  (void)in_sizes; (void)n_in; (void)out_size; (void)ws_size;
  const float* X     = (const float*)d_in[0];
  const float* Y     = (const float*)d_in[1];
  const float* Wih_e = (const float*)d_in[2];
  const float* Whh_e = (const float*)d_in[3];
  const float* bih_e = (const float*)d_in[4];
  const float* bhh_e = (const float*)d_in[5];
  const float* Wih_d = (const float*)d_in[6];
  const float* Whh_d = (const float*)d_in[7];
  const float* bih_d = (const float*)d_in[8];
  const float* bhh_d = (const float*)d_in[9];
  const float* Wd    = (const float*)d_in[10];
  const float* bd    = (const float*)d_in[11];
  const float* Wu    = (const float*)d_in[12];
  const float* bu    = (const float*)d_in[13];
  const float* Wv    = (const float*)d_in[14];
  const float* bv    = (const float*)d_in[15];
  const float* Wo    = (const float*)d_in[16];
  const float* bo    = (const float*)d_in[17];
  const float* Wlin  = (const float*)d_in[18];
  const float* blin  = (const float*)d_in[19];
  const float* h0    = (const float*)d_in[20];
  const float* c0    = (const float*)d_in[21];
  float* out = (float*)d_out;

  float* ws = (float*)d_ws;
  size_t o = 0;
  float* gatesXp = ws + o; o += (size_t)kT*kB*kG;        // 8,388,608
  float* WixT_e  = ws + o; o += (size_t)kIn*kG;
  float* WixT_d  = ws + o; o += (size_t)kIn*kG;
  float* WoT     = ws + o; o += (size_t)kH*kH;
  float* WlinT   = ws + o; o += (size_t)kH*kOut;
  float* Hdec    = ws + o; o += (size_t)128*kB*kH;       // 1,048,576
  float* wblob   = ws + o; o += (size_t)2*kSp*kWR*512;   // 589,824
  u64*   hbuf    = (u64*)(ws + o); o += (size_t)2*2*kB*kH; // 2 slots x 32 x 256 u64
  // hbuf tags are matched by equality to t in [0,256); 0xAA-poison never matches.

  auto tr = [&](float* dst, const float* src, int R, int C, int stride, int col0){
    int n = R*C;
    k_transpose<<<(n+255)/256, 256, 0, stream>>>(dst, src, R, C, stride, col0);
  };
  tr(WixT_e, Wih_e, kG, kIn, kIn+kM, 0);
  tr(WixT_d, Wih_d, kG, kIn, kIn+kM, 0);
  tr(WoT,   Wo,   kH,  kH, kH, 0);
  tr(WlinT, Wlin, kOut, kH, kH, 0);

  const int npack = kSp*kWR*512;
  k_packw<<<(npack+255)/256, 256, 0, stream>>>(wblob,                 Wih_e, Whh_e);
  k_packw<<<(npack+255)/256, 256, 0, stream>>>(wblob + (size_t)npack, Wih_d, Whh_d);

  k_gatesx<<<dim3(kT,4), 256, 0, stream>>>(X, Y, WixT_e, WixT_d,
                                           bih_e, bhh_e, bih_d, bhh_d, gatesXp);
  k_seq<<<kB*kSp, 512, 0, stream>>>(gatesXp, wblob, hbuf,
                                    Wd, bd, Wu, bu, Wv, bv, h0, c0, Hdec);
  k_out<<<128*kB, 256, 0, stream>>>(Hdec, WoT, bo, WlinT, blin, out);
}